// Round 18
// baseline (279.461 us; speedup 1.0000x reference)
//
#include <hip/hip_runtime.h>
#include <hip/hip_bf16.h>

#define BB 32
#define NN 32768
#define GG 64
#define KK 32
#define DD 384
#define EPSF 1e-5f
#define FPS_NBLK 8
#define FPS_SL   (NN/FPS_NBLK)

typedef __attribute__((ext_vector_type(8))) short short8;
typedef __attribute__((ext_vector_type(4))) float f32x4;

__device__ __forceinline__ float rn_add(float a, float b){ return __fadd_rn(a,b); }
__device__ __forceinline__ float rn_sub(float a, float b){ return __fsub_rn(a,b); }
__device__ __forceinline__ float rn_mul(float a, float b){ return __fmul_rn(a,b); }

__device__ __forceinline__ unsigned fkey(float d){
  unsigned u = __float_as_uint(d);
  return (u & 0x80000000u) ? ~u : (u | 0x80000000u);
}

__device__ __forceinline__ unsigned short f2bf(float f){
  unsigned u = __float_as_uint(f);
  unsigned r = (u + 0x7FFFu + ((u >> 16) & 1u)) >> 16;
  return (unsigned short)r;
}

#define REP8(X) X(0) X(1) X(2) X(3) X(4) X(5) X(6) X(7)

// ---- module-scope scratch ------------------------------------------------
__device__ float g_center[BB*GG*3];
__device__ int   g_knn[BB*GG*KK];
__device__ float g_w1t[6*64];
__device__ float g_b1[64];
__device__ float g_b2[128];
__device__ float g_b3[384];
__device__ __align__(16) unsigned short g_w2f[8*2*64*8];    // w2 MFMA frags
__device__ __align__(16) unsigned short g_w3f[24*4*64*8];   // w3 MFMA frags
__device__ float g_X[BB*NN];
__device__ float g_Y[BB*NN];
__device__ float g_Z[BB*NN];
__device__ float g_N2[BB*NN];
// fps exchange: per (b,sub,parity) 8 u64 (64B): [0]=key [1]=x [2]=y [3]=z
// key low word = ((it+1)<<15)|(32767-idx); coord slots = ((it+1)<<32)|bits.
// Every slot self-validates by tag -> ALL accesses relaxed (r15's acquire
// regression avoided). Parity x2 prevents overwrite races (a slot is only
// rewritten 2 rounds later, which requires all blocks past the old round).
__device__ unsigned long long g_slot[BB*FPS_NBLK*2*8];      // 32 KB

// ---------------------------------------------------------------------------
// One-shot AoS -> SoA repack + n2 precompute (bit-exact rn sequence).
// ---------------------------------------------------------------------------
__global__ __launch_bounds__(256) void k_soa(const float* __restrict__ xyz){
  int tid = blockIdx.x * blockDim.x + threadIdx.x;
  int b = tid >> 15;
  int p = tid & (NN - 1);
  const float* s = xyz + (size_t)b*NN*3 + (size_t)p*3;
  float x = s[0], y = s[1], z = s[2];
  g_X[tid] = x;
  g_Y[tid] = y;
  g_Z[tid] = z;
  g_N2[tid] = rn_add(rn_add(rn_mul(x,x), rn_mul(y,y)), rn_mul(z,z));
}

__global__ __launch_bounds__(256) void k_zero(void){
  int tid = blockIdx.x * blockDim.x + threadIdx.x;
  if (tid < BB*FPS_NBLK*2*8) g_slot[tid] = 0ull;
}

// ---------------------------------------------------------------------------
// Weight prep (validated r12): fold BN; w1 transposed f32; w2/w3 bf16 frags.
// ---------------------------------------------------------------------------
__global__ void k_prep(const float* __restrict__ w1, const float* __restrict__ g1, const float* __restrict__ b1, const float* __restrict__ m1, const float* __restrict__ v1,
                       const float* __restrict__ w2, const float* __restrict__ g2, const float* __restrict__ b2, const float* __restrict__ m2, const float* __restrict__ v2,
                       const float* __restrict__ w3, const float* __restrict__ g3, const float* __restrict__ b3, const float* __restrict__ m3, const float* __restrict__ v3){
  int tid = blockIdx.x * blockDim.x + threadIdx.x;
  int nt  = gridDim.x * blockDim.x;
  for (int e = tid; e < 64*6; e += nt){
    int c = e >> 6, o = e & 63;
    float s = g1[o] * rsqrtf(v1[o] + EPSF);
    g_w1t[e] = w1[o*6 + c] * s;
  }
  for (int o = tid; o < 64; o += nt){
    float s = g1[o] * rsqrtf(v1[o] + EPSF);
    g_b1[o] = b1[o] - m1[o]*s;
  }
  for (int o = tid; o < 128; o += nt){
    float s = g2[o] * rsqrtf(v2[o] + EPSF);
    g_b2[o] = b2[o] - m2[o]*s;
  }
  for (int o = tid; o < 384; o += nt){
    float s = g3[o] * rsqrtf(v3[o] + EPSF);
    g_b3[o] = b3[o] - m3[o]*s;
  }
  for (int idx = tid; idx < 8192; idx += nt){
    int e  = idx & 7;
    int l  = (idx >> 3) & 63;
    int kt = (idx >> 9) & 1;
    int ct = idx >> 10;
    int j  = ct*16 + (l & 15);
    int k  = kt*32 + ((l >> 4) << 3) + e;
    float s = g2[j] * rsqrtf(v2[j] + EPSF);
    g_w2f[idx] = f2bf(w2[j*64 + k] * s);
  }
  for (int idx = tid; idx < 49152; idx += nt){
    int e  = idx & 7;
    int l  = (idx >> 3) & 63;
    int kt = (idx >> 9) & 3;
    int ct = idx >> 11;
    int j  = ct*16 + (l & 15);
    int k  = kt*32 + ((l >> 4) << 3) + e;
    float s = g3[j] * rsqrtf(v3[j] + EPSF);
    g_w3f[idx] = f2bf(w3[j*128 + k] * s);
  }
}

// ---------------------------------------------------------------------------
// FPS v9 = r16-validated v8 with ONE change: winner coords ride the exchange
// in tagged relaxed slots, removing the dependent Xb/Yb/Zb[far] reload
// (~300-500cy) from the per-iteration critical path.
// ---------------------------------------------------------------------------
__global__ __launch_bounds__(512)
void k_fps(float* __restrict__ outCenter){
  const int blk = blockIdx.x;
  const int b   = blk & 31;          // batch (XCD co-location remap, r14)
  const int sub = blk >> 5;          // sub-block 0..7
  const int t   = threadIdx.x;
  const int wv  = t >> 6, ln = t & 63;
  const int base = sub * FPS_SL;
  const float* Xb = g_X + (size_t)b*NN;
  const float* Yb = g_Y + (size_t)b*NN;
  const float* Zb = g_Z + (size_t)b*NN;

  __shared__ float sx[FPS_SL], sy[FPS_SL], szz[FPS_SL];
  __shared__ unsigned long long skey[8];
  __shared__ float s_cx, s_cy, s_cz;

  #pragma unroll
  for (int i = 0; i < 8; ++i){
    int p = (i << 9) + t;
    sx[p]  = Xb[base + p];
    sy[p]  = Yb[base + p];
    szz[p] = Zb[base + p];
  }
  __syncthreads();

#define DD_DECL(i) float dd##i = 1e10f;
  REP8(DD_DECL)
#undef DD_DECL

  float cx = Xb[0], cy = Yb[0], cz = Zb[0];   // initial centroid = point 0

  for (int it = 0; ; ++it){
    if (sub == 0 && t == 0){
      float* cw = g_center  + (size_t)(b*GG + it)*3;
      float* co = outCenter + (size_t)(b*GG + it)*3;
      cw[0] = cx; cw[1] = cy; cw[2] = cz;
      co[0] = cx; co[1] = cy; co[2] = cz;
    }
    if (it == GG - 1) break;

    const unsigned tagv = (unsigned)(it + 1);
    unsigned long long bk = 0ull;
    // ascending i => ascending point idx; key low word = (tag<<15)|(32767-p):
    // tag constant within a round => max key == (max d, tie -> lowest idx).
#define DD_UPD(i) { \
    int p = (i << 9) + t; \
    float dx = rn_sub(sx[p], cx); \
    float dy = rn_sub(sy[p], cy); \
    float dz = rn_sub(szz[p], cz); \
    float s_ = rn_add(rn_add(rn_mul(dx,dx), rn_mul(dy,dy)), rn_mul(dz,dz)); \
    float d_ = fminf(dd##i, s_); \
    dd##i = d_; \
    unsigned long long k_ = ((unsigned long long)fkey(d_) << 32) \
                          | (tagv << 15) | (unsigned)(32767 - (base + p)); \
    if (k_ > bk) bk = k_; }
    REP8(DD_UPD)
#undef DD_UPD

    #pragma unroll
    for (int off = 32; off >= 1; off >>= 1){
      unsigned long long o = (unsigned long long)__shfl_xor((long long)bk, off);
      if (o > bk) bk = o;
    }
    if (ln == 0) skey[wv] = bk;
    __syncthreads();
    if (wv == 0){
      // block max over the 8 wave keys
      unsigned long long m = (ln < 8) ? skey[ln] : 0ull;
      #pragma unroll
      for (int off = 1; off <= 4; off <<= 1){
        unsigned long long o = (unsigned long long)__shfl_xor((long long)m, off);
        if (o > m) m = o;
      }
      if (ln == 0){
        int pl = (32767 - (int)(m & 0x7FFFu)) - base;   // own-slice local idx
        unsigned long long* S =
            &g_slot[((((b << 3) + sub) << 1) + (it & 1)) << 3];
        unsigned long long xv = ((unsigned long long)tagv << 32) | __float_as_uint(sx[pl]);
        unsigned long long yv = ((unsigned long long)tagv << 32) | __float_as_uint(sy[pl]);
        unsigned long long zv = ((unsigned long long)tagv << 32) | __float_as_uint(szz[pl]);
        __hip_atomic_store(S + 0, m,  __ATOMIC_RELAXED, __HIP_MEMORY_SCOPE_AGENT);
        __hip_atomic_store(S + 1, xv, __ATOMIC_RELAXED, __HIP_MEMORY_SCOPE_AGENT);
        __hip_atomic_store(S + 2, yv, __ATOMIC_RELAXED, __HIP_MEMORY_SCOPE_AGENT);
        __hip_atomic_store(S + 3, zv, __ATOMIC_RELAXED, __HIP_MEMORY_SCOPE_AGENT);
      }
      // parallel poll: lanes 0-31 = {key,x,y,z} x 8 subs, each self-validating
      unsigned long long v = 0ull;
      const int grp = ln >> 3, sb = ln & 7;
      if (ln < 32){
        unsigned long long* P =
            &g_slot[(((((b << 3) + sb) << 1) + (it & 1)) << 3) + grp];
        if (grp == 0){
          do { v = __hip_atomic_load(P, __ATOMIC_RELAXED, __HIP_MEMORY_SCOPE_AGENT); }
          while ((((unsigned)v) >> 15) != tagv);
        } else {
          do { v = __hip_atomic_load(P, __ATOMIC_RELAXED, __HIP_MEMORY_SCOPE_AGENT); }
          while ((unsigned)(v >> 32) != tagv);
        }
      }
      // winner among subs (keys in lanes 0-7), carry sub index
      unsigned long long k = (ln < 8) ? v : 0ull;
      int ws = sb;
      #pragma unroll
      for (int off = 1; off <= 4; off <<= 1){
        unsigned long long ok = (unsigned long long)__shfl_xor((long long)k, off);
        int ows = __shfl_xor(ws, off);
        if (ok > k){ k = ok; ws = ows; }
      }
      ws = __shfl(ws, 0);                    // broadcast winner sub
      unsigned long long vx = (unsigned long long)__shfl((long long)v,  8 + ws);
      unsigned long long vy = (unsigned long long)__shfl((long long)v, 16 + ws);
      unsigned long long vz = (unsigned long long)__shfl((long long)v, 24 + ws);
      if (ln == 0){
        s_cx = __uint_as_float((unsigned)(vx & 0xFFFFFFFFu));
        s_cy = __uint_as_float((unsigned)(vy & 0xFFFFFFFFu));
        s_cz = __uint_as_float((unsigned)(vz & 0xFFFFFFFFu));
      }
    }
    __syncthreads();
    cx = s_cx; cy = s_cy; cz = s_cz;
  }
}

// ---------------------------------------------------------------------------
// KNN v6 (validated r17): 4 centers/block, 512 blocks, sort-based T.
// ---------------------------------------------------------------------------
__global__ __launch_bounds__(256) void k_knn(void){
  const int j  = blockIdx.x;                    // 0..511
  const int b  = (j & 7) + ((j >> 7) << 3);     // batch 0..31
  const int g0 = ((j >> 3) & 15) << 2;          // first of 4 centers
  const int t  = threadIdx.x;
  const int w  = t >> 6;                        // wave 0..3
  const int ln = t & 63;
  const float4* X4 = (const float4*)(g_X  + (size_t)b*NN);
  const float4* Y4 = (const float4*)(g_Y  + (size_t)b*NN);
  const float4* Z4 = (const float4*)(g_Z  + (size_t)b*NN);
  const float4* N4 = (const float4*)(g_N2 + (size_t)b*NN);

  __shared__ float sC[4][4];
  __shared__ unsigned sE[4][64];
  __shared__ unsigned sTk[4];
  __shared__ unsigned long long cand[4][512];   // 16 KB
  __shared__ int cnt[4];

  if (t < 4){
    const float* cp = g_center + (size_t)(b*GG + g0 + t)*3;
    float x = cp[0], y = cp[1], z = cp[2];
    sC[0][t] = x; sC[1][t] = y; sC[2][t] = z;
    sC[3][t] = rn_add(rn_add(rn_mul(x,x), rn_mul(y,y)), rn_mul(z,z));
    cnt[t] = 0;
  }
  __syncthreads();

  float cx[4], cy[4], cz[4], cn[4];
  #pragma unroll
  for (int c = 0; c < 4; ++c){
    cx[c] = sC[0][c]; cy[c] = sC[1][c]; cz[c] = sC[2][c]; cn[c] = sC[3][c];
  }

  float e0[4], e1[4];
  #pragma unroll
  for (int c = 0; c < 4; ++c){ e0[c] = INFINITY; e1[c] = INFINITY; }
  #pragma unroll 2
  for (int s = 0; s < 32; ++s){
    int q = (s << 8) + t;
    float4 x = X4[q], y = Y4[q], z = Z4[q], n = N4[q];
    #pragma unroll
    for (int c = 0; c < 4; ++c){
      #define P1C(comp) { \
        float e = rn_add(rn_add(rn_mul(cx[c],x.comp), rn_mul(cy[c],y.comp)), rn_mul(cz[c],z.comp)); \
        float d = rn_sub(rn_add(cn[c], n.comp), rn_add(e,e)); \
        float nm2 = fminf(e1[c], fmaxf(e0[c], d)); \
        e0[c] = fminf(e0[c], d); \
        e1[c] = nm2; }
      P1C(x) P1C(y) P1C(z) P1C(w)
      #undef P1C
    }
  }

  #pragma unroll
  for (int c = 0; c < 4; ++c){
    unsigned v = fkey(e1[c]);
    #pragma unroll
    for (int k = 2; k <= 64; k <<= 1){
      #pragma unroll
      for (int jj = k >> 1; jj > 0; jj >>= 1){
        unsigned o = (unsigned)__shfl_xor((int)v, jj);
        bool keepmin = (((ln & k) == 0) == ((ln & jj) == 0));
        unsigned mn = o < v ? o : v;
        unsigned mx = o < v ? v : o;
        v = keepmin ? mn : mx;
      }
    }
    if (ln < 16) sE[c][w*16 + ln] = v;
  }
  __syncthreads();

  {
    unsigned v = sE[w][ln];
    #pragma unroll
    for (int k = 2; k <= 64; k <<= 1){
      #pragma unroll
      for (int jj = k >> 1; jj > 0; jj >>= 1){
        unsigned o = (unsigned)__shfl_xor((int)v, jj);
        bool keepmin = (((ln & k) == 0) == ((ln & jj) == 0));
        unsigned mn = o < v ? o : v;
        unsigned mx = o < v ? v : o;
        v = keepmin ? mn : mx;
      }
    }
    unsigned T = (unsigned)__shfl((int)v, 15);
    if (ln == 0) sTk[w] = T;
  }
  __syncthreads();

  unsigned Tr[4];
  #pragma unroll
  for (int c = 0; c < 4; ++c) Tr[c] = sTk[c];

  #pragma unroll 2
  for (int s = 0; s < 32; ++s){
    int q = (s << 8) + t;
    float4 x = X4[q], y = Y4[q], z = Z4[q], n = N4[q];
    #pragma unroll
    for (int c = 0; c < 4; ++c){
      #define P2C(comp, kk) { \
        float e = rn_add(rn_add(rn_mul(cx[c],x.comp), rn_mul(cy[c],y.comp)), rn_mul(cz[c],z.comp)); \
        float d = rn_sub(rn_add(cn[c], n.comp), rn_add(e,e)); \
        unsigned fk = fkey(d); \
        if (fk <= Tr[c]){ \
          int p = atomicAdd(&cnt[c], 1); \
          if (p < 512) \
            cand[c][p] = ((unsigned long long)fk << 32) | (unsigned)((q<<2)+kk); } }
      P2C(x,0) P2C(y,1) P2C(z,2) P2C(w,3)
      #undef P2C
    }
  }
  __syncthreads();

  {
    int C = cnt[w]; if (C > 512) C = 512;
    int* kout = g_knn + (size_t)(b*GG + g0 + w)*KK;
    if (C <= 64){
      unsigned long long kk = (ln < C) ? cand[w][ln] : ~0ull;
      #pragma unroll
      for (int k = 2; k <= 64; k <<= 1){
        #pragma unroll
        for (int jj = k >> 1; jj > 0; jj >>= 1){
          unsigned long long o = (unsigned long long)__shfl_xor((long long)kk, jj);
          bool keepmin = (((ln & k) == 0) == ((ln & jj) == 0));
          unsigned long long mn = o < kk ? o : kk;
          unsigned long long mx = o < kk ? kk : o;
          kk = keepmin ? mn : mx;
        }
      }
      if (ln < KK) kout[ln] = (int)(kk & 0xffffffffu);
    } else {
      unsigned long long md[8];
      #pragma unroll
      for (int jj = 0; jj < 8; ++jj){
        int e = ln + (jj << 6);
        md[jj] = (e < C) ? cand[w][e] : ~0ull;
      }
      for (int r = 0; r < KK; ++r){
        unsigned long long bk = md[0];
        #pragma unroll
        for (int jj = 1; jj < 8; ++jj) if (md[jj] < bk) bk = md[jj];
        #pragma unroll
        for (int off = 32; off >= 1; off >>= 1){
          unsigned long long o = (unsigned long long)__shfl_xor((long long)bk, off);
          if (o < bk) bk = o;
        }
        #pragma unroll
        for (int jj = 0; jj < 8; ++jj) if (md[jj] == bk) md[jj] = ~0ull;
        if (ln == 0) kout[r] = (int)(bk & 0xffffffffu);
      }
    }
  }
}

// ---------------------------------------------------------------------------
// MLP v2 (validated r12): L1 VALU; L2/L3 mfma_f32_16x16x32_bf16.
// ---------------------------------------------------------------------------
__global__ __launch_bounds__(256) void k_mlp(const float* __restrict__ xyz,
                                             const float* __restrict__ feat,
                                             float* __restrict__ outPatch){
  const int bg = blockIdx.x;
  const int b  = bg >> 6;
  const int t  = threadIdx.x;
  const int w  = t >> 6;
  const int ln = t & 63;
  const float* xb = xyz  + (size_t)b*NN*3;
  const float* fb = feat + (size_t)b*NN*3;

  __shared__ float h0[KK][8];
  __shared__ __align__(16) unsigned short h1b[KK][72];
  __shared__ __align__(16) unsigned short h2b[KK][136];

  if (t < KK){
    int idx = g_knn[(size_t)bg*KK + t] & (NN - 1);
    const float* cp = g_center + (size_t)bg*3;
    h0[t][0] = rn_sub(xb[idx*3+0], cp[0]);
    h0[t][1] = rn_sub(xb[idx*3+1], cp[1]);
    h0[t][2] = rn_sub(xb[idx*3+2], cp[2]);
    h0[t][3] = fb[idx*3+0];
    h0[t][4] = fb[idx*3+1];
    h0[t][5] = fb[idx*3+2];
  }
  __syncthreads();

  {
    int p = t >> 3, ob = (t & 7) * 8;
    float acc[8];
    #pragma unroll
    for (int j = 0; j < 8; ++j) acc[j] = g_b1[ob + j];
    #pragma unroll
    for (int c = 0; c < 6; ++c){
      float a = h0[p][c];
      const float4* wr = (const float4*)(g_w1t + c*64 + ob);
      float4 wa = wr[0], wb = wr[1];
      acc[0] = fmaf(a, wa.x, acc[0]); acc[1] = fmaf(a, wa.y, acc[1]);
      acc[2] = fmaf(a, wa.z, acc[2]); acc[3] = fmaf(a, wa.w, acc[3]);
      acc[4] = fmaf(a, wb.x, acc[4]); acc[5] = fmaf(a, wb.y, acc[5]);
      acc[6] = fmaf(a, wb.z, acc[6]); acc[7] = fmaf(a, wb.w, acc[7]);
    }
    short8 v;
    #pragma unroll
    for (int j = 0; j < 8; ++j) v[j] = (short)f2bf(fmaxf(acc[j], 0.f));
    *reinterpret_cast<short8*>(&h1b[p][ob]) = v;
  }
  __syncthreads();

  {
    f32x4 a00 = {0,0,0,0}, a01 = {0,0,0,0}, a10 = {0,0,0,0}, a11 = {0,0,0,0};
    const int g8 = (ln >> 4) << 3;
    #pragma unroll
    for (int kk = 0; kk < 2; ++kk){
      short8 A0 = *reinterpret_cast<const short8*>(&h1b[(ln & 15)][kk*32 + g8]);
      short8 A1 = *reinterpret_cast<const short8*>(&h1b[16 + (ln & 15)][kk*32 + g8]);
      short8 B0 = *reinterpret_cast<const short8*>(&g_w2f[(((2*w+0)*2 + kk)*64 + ln)*8]);
      short8 B1 = *reinterpret_cast<const short8*>(&g_w2f[(((2*w+1)*2 + kk)*64 + ln)*8]);
      a00 = __builtin_amdgcn_mfma_f32_16x16x32_bf16(A0, B0, a00, 0, 0, 0);
      a01 = __builtin_amdgcn_mfma_f32_16x16x32_bf16(A1, B0, a01, 0, 0, 0);
      a10 = __builtin_amdgcn_mfma_f32_16x16x32_bf16(A0, B1, a10, 0, 0, 0);
      a11 = __builtin_amdgcn_mfma_f32_16x16x32_bf16(A1, B1, a11, 0, 0, 0);
    }
    int col0 = (2*w)*16 + (ln & 15);
    int col1 = col0 + 16;
    float bz0 = g_b2[col0], bz1 = g_b2[col1];
    int r0 = (ln >> 4) << 2;
    #pragma unroll
    for (int r = 0; r < 4; ++r){
      h2b[r0 + r][col0]      = f2bf(fmaxf(a00[r] + bz0, 0.f));
      h2b[16 + r0 + r][col0] = f2bf(fmaxf(a01[r] + bz0, 0.f));
      h2b[r0 + r][col1]      = f2bf(fmaxf(a10[r] + bz1, 0.f));
      h2b[16 + r0 + r][col1] = f2bf(fmaxf(a11[r] + bz1, 0.f));
    }
  }
  __syncthreads();

  {
    f32x4 acc3[6][2];
    #pragma unroll
    for (int ci = 0; ci < 6; ++ci){
      acc3[ci][0] = (f32x4){0,0,0,0};
      acc3[ci][1] = (f32x4){0,0,0,0};
    }
    const int g8 = (ln >> 4) << 3;
    #pragma unroll
    for (int kk = 0; kk < 4; ++kk){
      short8 A0 = *reinterpret_cast<const short8*>(&h2b[(ln & 15)][kk*32 + g8]);
      short8 A1 = *reinterpret_cast<const short8*>(&h2b[16 + (ln & 15)][kk*32 + g8]);
      #pragma unroll
      for (int ci = 0; ci < 6; ++ci){
        int ct = w*6 + ci;
        short8 B = *reinterpret_cast<const short8*>(&g_w3f[((ct*4 + kk)*64 + ln)*8]);
        acc3[ci][0] = __builtin_amdgcn_mfma_f32_16x16x32_bf16(A0, B, acc3[ci][0], 0, 0, 0);
        acc3[ci][1] = __builtin_amdgcn_mfma_f32_16x16x32_bf16(A1, B, acc3[ci][1], 0, 0, 0);
      }
    }
    #pragma unroll
    for (int ci = 0; ci < 6; ++ci){
      float m = acc3[ci][0][0];
      #pragma unroll
      for (int r = 1; r < 4; ++r) m = fmaxf(m, acc3[ci][0][r]);
      #pragma unroll
      for (int r = 0; r < 4; ++r) m = fmaxf(m, acc3[ci][1][r]);
      m = fmaxf(m, __shfl_xor(m, 16));
      m = fmaxf(m, __shfl_xor(m, 32));
      if (ln < 16){
        int col = (w*6 + ci)*16 + ln;
        outPatch[(size_t)bg*DD + col] = m + g_b3[col];
      }
    }
  }
}

// ---------------------------------------------------------------------------
extern "C" void kernel_launch(void* const* d_in, const int* in_sizes, int n_in,
                              void* d_out, int out_size, void* d_ws, size_t ws_size,
                              hipStream_t stream){
  (void)in_sizes; (void)n_in; (void)out_size; (void)d_ws; (void)ws_size;
  const float* xyz  = (const float*)d_in[0];
  const float* feat = (const float*)d_in[1];
  const float* w1 = (const float*)d_in[2];
  const float* g1 = (const float*)d_in[3];
  const float* b1 = (const float*)d_in[4];
  const float* m1 = (const float*)d_in[5];
  const float* v1 = (const float*)d_in[6];
  const float* w2 = (const float*)d_in[7];
  const float* g2 = (const float*)d_in[8];
  const float* b2 = (const float*)d_in[9];
  const float* m2 = (const float*)d_in[10];
  const float* v2 = (const float*)d_in[11];
  const float* w3 = (const float*)d_in[12];
  const float* g3 = (const float*)d_in[13];
  const float* b3 = (const float*)d_in[14];
  const float* m3 = (const float*)d_in[15];
  const float* v3 = (const float*)d_in[16];
  float* out = (float*)d_out;

  k_prep<<<64, 256, 0, stream>>>(w1,g1,b1,m1,v1, w2,g2,b2,m2,v2, w3,g3,b3,m3,v3);
  k_soa<<<(BB*NN)/256, 256, 0, stream>>>(xyz);
  k_zero<<<2, 256, 0, stream>>>();
  k_fps<<<BB*FPS_NBLK, 512, 0, stream>>>(out);
  k_knn<<<512, 256, 0, stream>>>();
  k_mlp<<<BB*GG, 256, 0, stream>>>(xyz, feat, out + (size_t)BB*GG*3);
}

// Round 19
// 247.984 us; speedup vs baseline: 1.1269x; 1.1269x over previous
//
#include <hip/hip_runtime.h>
#include <hip/hip_bf16.h>

#define BB 32
#define NN 32768
#define GG 64
#define KK 32
#define DD 384
#define EPSF 1e-5f
#define FPS_NBLK 8
#define FPS_SL   (NN/FPS_NBLK)

typedef __attribute__((ext_vector_type(8))) short short8;
typedef __attribute__((ext_vector_type(4))) float f32x4;

__device__ __forceinline__ float rn_add(float a, float b){ return __fadd_rn(a,b); }
__device__ __forceinline__ float rn_sub(float a, float b){ return __fsub_rn(a,b); }
__device__ __forceinline__ float rn_mul(float a, float b){ return __fmul_rn(a,b); }

__device__ __forceinline__ unsigned fkey(float d){
  unsigned u = __float_as_uint(d);
  return (u & 0x80000000u) ? ~u : (u | 0x80000000u);
}

__device__ __forceinline__ unsigned short f2bf(float f){
  unsigned u = __float_as_uint(f);
  unsigned r = (u + 0x7FFFu + ((u >> 16) & 1u)) >> 16;
  return (unsigned short)r;
}

#define REP8(X) X(0) X(1) X(2) X(3) X(4) X(5) X(6) X(7)

// ---- module-scope scratch ------------------------------------------------
__device__ float g_center[BB*GG*3];
__device__ int   g_knn[BB*GG*KK];
__device__ float g_w1t[6*64];
__device__ float g_b1[64];
__device__ float g_b2[128];
__device__ float g_b3[384];
__device__ __align__(16) unsigned short g_w2f[8*2*64*8];    // w2 MFMA frags
__device__ __align__(16) unsigned short g_w3f[24*4*64*8];   // w3 MFMA frags
__device__ float g_X[BB*NN];
__device__ float g_Y[BB*NN];
__device__ float g_Z[BB*NN];
__device__ float g_N2[BB*NN];
__device__ unsigned long long g_part[BB*FPS_NBLK*GG];

// ---------------------------------------------------------------------------
// One-shot AoS -> SoA repack + n2 precompute (bit-exact rn sequence).
// ---------------------------------------------------------------------------
__global__ __launch_bounds__(256) void k_soa(const float* __restrict__ xyz){
  int tid = blockIdx.x * blockDim.x + threadIdx.x;
  int b = tid >> 15;
  int p = tid & (NN - 1);
  const float* s = xyz + (size_t)b*NN*3 + (size_t)p*3;
  float x = s[0], y = s[1], z = s[2];
  g_X[tid] = x;
  g_Y[tid] = y;
  g_Z[tid] = z;
  g_N2[tid] = rn_add(rn_add(rn_mul(x,x), rn_mul(y,y)), rn_mul(z,z));
}

__global__ __launch_bounds__(256) void k_zero(void){
  int tid = blockIdx.x * blockDim.x + threadIdx.x;
  if (tid < BB*FPS_NBLK*GG) g_part[tid] = 0ull;
}

// ---------------------------------------------------------------------------
// Weight prep (validated r12): fold BN; w1 transposed f32; w2/w3 bf16 frags.
// ---------------------------------------------------------------------------
__global__ void k_prep(const float* __restrict__ w1, const float* __restrict__ g1, const float* __restrict__ b1, const float* __restrict__ m1, const float* __restrict__ v1,
                       const float* __restrict__ w2, const float* __restrict__ g2, const float* __restrict__ b2, const float* __restrict__ m2, const float* __restrict__ v2,
                       const float* __restrict__ w3, const float* __restrict__ g3, const float* __restrict__ b3, const float* __restrict__ m3, const float* __restrict__ v3){
  int tid = blockIdx.x * blockDim.x + threadIdx.x;
  int nt  = gridDim.x * blockDim.x;
  for (int e = tid; e < 64*6; e += nt){
    int c = e >> 6, o = e & 63;
    float s = g1[o] * rsqrtf(v1[o] + EPSF);
    g_w1t[e] = w1[o*6 + c] * s;
  }
  for (int o = tid; o < 64; o += nt){
    float s = g1[o] * rsqrtf(v1[o] + EPSF);
    g_b1[o] = b1[o] - m1[o]*s;
  }
  for (int o = tid; o < 128; o += nt){
    float s = g2[o] * rsqrtf(v2[o] + EPSF);
    g_b2[o] = b2[o] - m2[o]*s;
  }
  for (int o = tid; o < 384; o += nt){
    float s = g3[o] * rsqrtf(v3[o] + EPSF);
    g_b3[o] = b3[o] - m3[o]*s;
  }
  for (int idx = tid; idx < 8192; idx += nt){
    int e  = idx & 7;
    int l  = (idx >> 3) & 63;
    int kt = (idx >> 9) & 1;
    int ct = idx >> 10;
    int j  = ct*16 + (l & 15);
    int k  = kt*32 + ((l >> 4) << 3) + e;
    float s = g2[j] * rsqrtf(v2[j] + EPSF);
    g_w2f[idx] = f2bf(w2[j*64 + k] * s);
  }
  for (int idx = tid; idx < 49152; idx += nt){
    int e  = idx & 7;
    int l  = (idx >> 3) & 63;
    int kt = (idx >> 9) & 3;
    int ct = idx >> 11;
    int j  = ct*16 + (l & 15);
    int k  = kt*32 + ((l >> 4) << 3) + e;
    float s = g3[j] * rsqrtf(v3[j] + EPSF);
    g_w3f[idx] = f2bf(w3[j*128 + k] * s);
  }
}

// ---------------------------------------------------------------------------
// FPS v8 (validated r16/r17): 512 threads, relaxed store/poll exchange,
// XCD co-location remap. ~1.97us/iter = the structural floor for this
// multi-block design (63 sequential device-scope argmax rounds; coords-in-
// slots variants regressed twice, r15/r18).
// ---------------------------------------------------------------------------
__global__ __launch_bounds__(512)
void k_fps(float* __restrict__ outCenter){
  const int blk = blockIdx.x;
  const int b   = blk & 31;
  const int sub = blk >> 5;
  const int t   = threadIdx.x;
  const int wv  = t >> 6, ln = t & 63;
  const int base = sub * FPS_SL;
  const float* Xb = g_X + (size_t)b*NN;
  const float* Yb = g_Y + (size_t)b*NN;
  const float* Zb = g_Z + (size_t)b*NN;

  __shared__ float sx[FPS_SL], sy[FPS_SL], szz[FPS_SL];
  __shared__ unsigned long long skey[8];
  __shared__ int s_far;

  #pragma unroll
  for (int i = 0; i < 8; ++i){
    int p = (i << 9) + t;
    sx[p]  = Xb[base + p];
    sy[p]  = Yb[base + p];
    szz[p] = Zb[base + p];
  }
  __syncthreads();

#define DD_DECL(i) float dd##i = 1e10f;
  REP8(DD_DECL)
#undef DD_DECL

  int far = 0;
  for (int it = 0; ; ++it){
    if (sub == 0 && t == 0){
      float cx = Xb[far], cy = Yb[far], cz = Zb[far];
      float* cw = g_center  + (size_t)(b*GG + it)*3;
      float* co = outCenter + (size_t)(b*GG + it)*3;
      cw[0] = cx; cw[1] = cy; cw[2] = cz;
      co[0] = cx; co[1] = cy; co[2] = cz;
    }
    if (it == GG - 1) break;

    float cx = Xb[far], cy = Yb[far], cz = Zb[far];
    unsigned long long bk = 0ull;
#define DD_UPD(i) { \
    int p = (i << 9) + t; \
    float dx = rn_sub(sx[p], cx); \
    float dy = rn_sub(sy[p], cy); \
    float dz = rn_sub(szz[p], cz); \
    float s_ = rn_add(rn_add(rn_mul(dx,dx), rn_mul(dy,dy)), rn_mul(dz,dz)); \
    float d_ = fminf(dd##i, s_); \
    dd##i = d_; \
    unsigned long long k_ = ((unsigned long long)fkey(d_) << 32) \
                          | (unsigned)(0xFFFFFFFFu - (unsigned)(base + p)); \
    if (k_ > bk) bk = k_; }
    REP8(DD_UPD)
#undef DD_UPD

    #pragma unroll
    for (int off = 32; off >= 1; off >>= 1){
      unsigned long long o = (unsigned long long)__shfl_xor((long long)bk, off);
      if (o > bk) bk = o;
    }
    if (ln == 0) skey[wv] = bk;
    __syncthreads();
    if (wv == 0){
      unsigned long long m = (ln < 8) ? skey[ln] : 0ull;
      #pragma unroll
      for (int off = 1; off <= 4; off <<= 1){
        unsigned long long o = (unsigned long long)__shfl_xor((long long)m, off);
        if (o > m) m = o;
      }
      if (ln == 0)
        __hip_atomic_store(&g_part[(((b << 3) + sub) << 6) + it], m,
                           __ATOMIC_RELAXED, __HIP_MEMORY_SCOPE_AGENT);
      unsigned long long k = 0ull;
      if (ln < 8){
        unsigned long long* p = &g_part[(((b << 3) + ln) << 6) + it];
        do {
          k = __hip_atomic_load(p, __ATOMIC_RELAXED, __HIP_MEMORY_SCOPE_AGENT);
        } while (k == 0ull);
      }
      #pragma unroll
      for (int off = 1; off <= 4; off <<= 1){
        unsigned long long o = (unsigned long long)__shfl_xor((long long)k, off);
        if (o > k) k = o;
      }
      if (ln == 0) s_far = (int)(0xFFFFFFFFu - (unsigned)(k & 0xFFFFFFFFu));
    }
    __syncthreads();
    far = s_far;
  }
}

// ---------------------------------------------------------------------------
// KNN v6 (validated r17): 4 centers/block, 512 blocks (2 blocks/CU,
// 8 waves/CU), traffic amortized 4x vs v4, sort-based exact T.
// ---------------------------------------------------------------------------
__global__ __launch_bounds__(256) void k_knn(void){
  const int j  = blockIdx.x;                    // 0..511
  const int b  = (j & 7) + ((j >> 7) << 3);     // batch 0..31
  const int g0 = ((j >> 3) & 15) << 2;          // first of 4 centers
  const int t  = threadIdx.x;
  const int w  = t >> 6;                        // wave 0..3
  const int ln = t & 63;
  const float4* X4 = (const float4*)(g_X  + (size_t)b*NN);
  const float4* Y4 = (const float4*)(g_Y  + (size_t)b*NN);
  const float4* Z4 = (const float4*)(g_Z  + (size_t)b*NN);
  const float4* N4 = (const float4*)(g_N2 + (size_t)b*NN);

  __shared__ float sC[4][4];
  __shared__ unsigned sE[4][64];
  __shared__ unsigned sTk[4];
  __shared__ unsigned long long cand[4][512];   // 16 KB
  __shared__ int cnt[4];

  if (t < 4){
    const float* cp = g_center + (size_t)(b*GG + g0 + t)*3;
    float x = cp[0], y = cp[1], z = cp[2];
    sC[0][t] = x; sC[1][t] = y; sC[2][t] = z;
    sC[3][t] = rn_add(rn_add(rn_mul(x,x), rn_mul(y,y)), rn_mul(z,z));
    cnt[t] = 0;
  }
  __syncthreads();

  float cx[4], cy[4], cz[4], cn[4];
  #pragma unroll
  for (int c = 0; c < 4; ++c){
    cx[c] = sC[0][c]; cy[c] = sC[1][c]; cz[c] = sC[2][c]; cn[c] = sC[3][c];
  }

  float e0[4], e1[4];
  #pragma unroll
  for (int c = 0; c < 4; ++c){ e0[c] = INFINITY; e1[c] = INFINITY; }
  #pragma unroll 2
  for (int s = 0; s < 32; ++s){
    int q = (s << 8) + t;
    float4 x = X4[q], y = Y4[q], z = Z4[q], n = N4[q];
    #pragma unroll
    for (int c = 0; c < 4; ++c){
      #define P1C(comp) { \
        float e = rn_add(rn_add(rn_mul(cx[c],x.comp), rn_mul(cy[c],y.comp)), rn_mul(cz[c],z.comp)); \
        float d = rn_sub(rn_add(cn[c], n.comp), rn_add(e,e)); \
        float nm2 = fminf(e1[c], fmaxf(e0[c], d)); \
        e0[c] = fminf(e0[c], d); \
        e1[c] = nm2; }
      P1C(x) P1C(y) P1C(z) P1C(w)
      #undef P1C
    }
  }

  #pragma unroll
  for (int c = 0; c < 4; ++c){
    unsigned v = fkey(e1[c]);
    #pragma unroll
    for (int k = 2; k <= 64; k <<= 1){
      #pragma unroll
      for (int jj = k >> 1; jj > 0; jj >>= 1){
        unsigned o = (unsigned)__shfl_xor((int)v, jj);
        bool keepmin = (((ln & k) == 0) == ((ln & jj) == 0));
        unsigned mn = o < v ? o : v;
        unsigned mx = o < v ? v : o;
        v = keepmin ? mn : mx;
      }
    }
    if (ln < 16) sE[c][w*16 + ln] = v;
  }
  __syncthreads();

  {
    unsigned v = sE[w][ln];
    #pragma unroll
    for (int k = 2; k <= 64; k <<= 1){
      #pragma unroll
      for (int jj = k >> 1; jj > 0; jj >>= 1){
        unsigned o = (unsigned)__shfl_xor((int)v, jj);
        bool keepmin = (((ln & k) == 0) == ((ln & jj) == 0));
        unsigned mn = o < v ? o : v;
        unsigned mx = o < v ? v : o;
        v = keepmin ? mn : mx;
      }
    }
    unsigned T = (unsigned)__shfl((int)v, 15);
    if (ln == 0) sTk[w] = T;
  }
  __syncthreads();

  unsigned Tr[4];
  #pragma unroll
  for (int c = 0; c < 4; ++c) Tr[c] = sTk[c];

  #pragma unroll 2
  for (int s = 0; s < 32; ++s){
    int q = (s << 8) + t;
    float4 x = X4[q], y = Y4[q], z = Z4[q], n = N4[q];
    #pragma unroll
    for (int c = 0; c < 4; ++c){
      #define P2C(comp, kk) { \
        float e = rn_add(rn_add(rn_mul(cx[c],x.comp), rn_mul(cy[c],y.comp)), rn_mul(cz[c],z.comp)); \
        float d = rn_sub(rn_add(cn[c], n.comp), rn_add(e,e)); \
        unsigned fk = fkey(d); \
        if (fk <= Tr[c]){ \
          int p = atomicAdd(&cnt[c], 1); \
          if (p < 512) \
            cand[c][p] = ((unsigned long long)fk << 32) | (unsigned)((q<<2)+kk); } }
      P2C(x,0) P2C(y,1) P2C(z,2) P2C(w,3)
      #undef P2C
    }
  }
  __syncthreads();

  {
    int C = cnt[w]; if (C > 512) C = 512;
    int* kout = g_knn + (size_t)(b*GG + g0 + w)*KK;
    if (C <= 64){
      unsigned long long kk = (ln < C) ? cand[w][ln] : ~0ull;
      #pragma unroll
      for (int k = 2; k <= 64; k <<= 1){
        #pragma unroll
        for (int jj = k >> 1; jj > 0; jj >>= 1){
          unsigned long long o = (unsigned long long)__shfl_xor((long long)kk, jj);
          bool keepmin = (((ln & k) == 0) == ((ln & jj) == 0));
          unsigned long long mn = o < kk ? o : kk;
          unsigned long long mx = o < kk ? kk : o;
          kk = keepmin ? mn : mx;
        }
      }
      if (ln < KK) kout[ln] = (int)(kk & 0xffffffffu);
    } else {
      unsigned long long md[8];
      #pragma unroll
      for (int jj = 0; jj < 8; ++jj){
        int e = ln + (jj << 6);
        md[jj] = (e < C) ? cand[w][e] : ~0ull;
      }
      for (int r = 0; r < KK; ++r){
        unsigned long long bk = md[0];
        #pragma unroll
        for (int jj = 1; jj < 8; ++jj) if (md[jj] < bk) bk = md[jj];
        #pragma unroll
        for (int off = 32; off >= 1; off >>= 1){
          unsigned long long o = (unsigned long long)__shfl_xor((long long)bk, off);
          if (o < bk) bk = o;
        }
        #pragma unroll
        for (int jj = 0; jj < 8; ++jj) if (md[jj] == bk) md[jj] = ~0ull;
        if (ln == 0) kout[r] = (int)(bk & 0xffffffffu);
      }
    }
  }
}

// ---------------------------------------------------------------------------
// MLP v2 (validated r12): L1 VALU; L2/L3 mfma_f32_16x16x32_bf16.
// ---------------------------------------------------------------------------
__global__ __launch_bounds__(256) void k_mlp(const float* __restrict__ xyz,
                                             const float* __restrict__ feat,
                                             float* __restrict__ outPatch){
  const int bg = blockIdx.x;
  const int b  = bg >> 6;
  const int t  = threadIdx.x;
  const int w  = t >> 6;
  const int ln = t & 63;
  const float* xb = xyz  + (size_t)b*NN*3;
  const float* fb = feat + (size_t)b*NN*3;

  __shared__ float h0[KK][8];
  __shared__ __align__(16) unsigned short h1b[KK][72];
  __shared__ __align__(16) unsigned short h2b[KK][136];

  if (t < KK){
    int idx = g_knn[(size_t)bg*KK + t] & (NN - 1);
    const float* cp = g_center + (size_t)bg*3;
    h0[t][0] = rn_sub(xb[idx*3+0], cp[0]);
    h0[t][1] = rn_sub(xb[idx*3+1], cp[1]);
    h0[t][2] = rn_sub(xb[idx*3+2], cp[2]);
    h0[t][3] = fb[idx*3+0];
    h0[t][4] = fb[idx*3+1];
    h0[t][5] = fb[idx*3+2];
  }
  __syncthreads();

  {
    int p = t >> 3, ob = (t & 7) * 8;
    float acc[8];
    #pragma unroll
    for (int j = 0; j < 8; ++j) acc[j] = g_b1[ob + j];
    #pragma unroll
    for (int c = 0; c < 6; ++c){
      float a = h0[p][c];
      const float4* wr = (const float4*)(g_w1t + c*64 + ob);
      float4 wa = wr[0], wb = wr[1];
      acc[0] = fmaf(a, wa.x, acc[0]); acc[1] = fmaf(a, wa.y, acc[1]);
      acc[2] = fmaf(a, wa.z, acc[2]); acc[3] = fmaf(a, wa.w, acc[3]);
      acc[4] = fmaf(a, wb.x, acc[4]); acc[5] = fmaf(a, wb.y, acc[5]);
      acc[6] = fmaf(a, wb.z, acc[6]); acc[7] = fmaf(a, wb.w, acc[7]);
    }
    short8 v;
    #pragma unroll
    for (int j = 0; j < 8; ++j) v[j] = (short)f2bf(fmaxf(acc[j], 0.f));
    *reinterpret_cast<short8*>(&h1b[p][ob]) = v;
  }
  __syncthreads();

  {
    f32x4 a00 = {0,0,0,0}, a01 = {0,0,0,0}, a10 = {0,0,0,0}, a11 = {0,0,0,0};
    const int g8 = (ln >> 4) << 3;
    #pragma unroll
    for (int kk = 0; kk < 2; ++kk){
      short8 A0 = *reinterpret_cast<const short8*>(&h1b[(ln & 15)][kk*32 + g8]);
      short8 A1 = *reinterpret_cast<const short8*>(&h1b[16 + (ln & 15)][kk*32 + g8]);
      short8 B0 = *reinterpret_cast<const short8*>(&g_w2f[(((2*w+0)*2 + kk)*64 + ln)*8]);
      short8 B1 = *reinterpret_cast<const short8*>(&g_w2f[(((2*w+1)*2 + kk)*64 + ln)*8]);
      a00 = __builtin_amdgcn_mfma_f32_16x16x32_bf16(A0, B0, a00, 0, 0, 0);
      a01 = __builtin_amdgcn_mfma_f32_16x16x32_bf16(A1, B0, a01, 0, 0, 0);
      a10 = __builtin_amdgcn_mfma_f32_16x16x32_bf16(A0, B1, a10, 0, 0, 0);
      a11 = __builtin_amdgcn_mfma_f32_16x16x32_bf16(A1, B1, a11, 0, 0, 0);
    }
    int col0 = (2*w)*16 + (ln & 15);
    int col1 = col0 + 16;
    float bz0 = g_b2[col0], bz1 = g_b2[col1];
    int r0 = (ln >> 4) << 2;
    #pragma unroll
    for (int r = 0; r < 4; ++r){
      h2b[r0 + r][col0]      = f2bf(fmaxf(a00[r] + bz0, 0.f));
      h2b[16 + r0 + r][col0] = f2bf(fmaxf(a01[r] + bz0, 0.f));
      h2b[r0 + r][col1]      = f2bf(fmaxf(a10[r] + bz1, 0.f));
      h2b[16 + r0 + r][col1] = f2bf(fmaxf(a11[r] + bz1, 0.f));
    }
  }
  __syncthreads();

  {
    f32x4 acc3[6][2];
    #pragma unroll
    for (int ci = 0; ci < 6; ++ci){
      acc3[ci][0] = (f32x4){0,0,0,0};
      acc3[ci][1] = (f32x4){0,0,0,0};
    }
    const int g8 = (ln >> 4) << 3;
    #pragma unroll
    for (int kk = 0; kk < 4; ++kk){
      short8 A0 = *reinterpret_cast<const short8*>(&h2b[(ln & 15)][kk*32 + g8]);
      short8 A1 = *reinterpret_cast<const short8*>(&h2b[16 + (ln & 15)][kk*32 + g8]);
      #pragma unroll
      for (int ci = 0; ci < 6; ++ci){
        int ct = w*6 + ci;
        short8 B = *reinterpret_cast<const short8*>(&g_w3f[((ct*4 + kk)*64 + ln)*8]);
        acc3[ci][0] = __builtin_amdgcn_mfma_f32_16x16x32_bf16(A0, B, acc3[ci][0], 0, 0, 0);
        acc3[ci][1] = __builtin_amdgcn_mfma_f32_16x16x32_bf16(A1, B, acc3[ci][1], 0, 0, 0);
      }
    }
    #pragma unroll
    for (int ci = 0; ci < 6; ++ci){
      float m = acc3[ci][0][0];
      #pragma unroll
      for (int r = 1; r < 4; ++r) m = fmaxf(m, acc3[ci][0][r]);
      #pragma unroll
      for (int r = 0; r < 4; ++r) m = fmaxf(m, acc3[ci][1][r]);
      m = fmaxf(m, __shfl_xor(m, 16));
      m = fmaxf(m, __shfl_xor(m, 32));
      if (ln < 16){
        int col = (w*6 + ci)*16 + ln;
        outPatch[(size_t)bg*DD + col] = m + g_b3[col];
      }
    }
  }
}

// ---------------------------------------------------------------------------
extern "C" void kernel_launch(void* const* d_in, const int* in_sizes, int n_in,
                              void* d_out, int out_size, void* d_ws, size_t ws_size,
                              hipStream_t stream){
  (void)in_sizes; (void)n_in; (void)out_size; (void)d_ws; (void)ws_size;
  const float* xyz  = (const float*)d_in[0];
  const float* feat = (const float*)d_in[1];
  const float* w1 = (const float*)d_in[2];
  const float* g1 = (const float*)d_in[3];
  const float* b1 = (const float*)d_in[4];
  const float* m1 = (const float*)d_in[5];
  const float* v1 = (const float*)d_in[6];
  const float* w2 = (const float*)d_in[7];
  const float* g2 = (const float*)d_in[8];
  const float* b2 = (const float*)d_in[9];
  const float* m2 = (const float*)d_in[10];
  const float* v2 = (const float*)d_in[11];
  const float* w3 = (const float*)d_in[12];
  const float* g3 = (const float*)d_in[13];
  const float* b3 = (const float*)d_in[14];
  const float* m3 = (const float*)d_in[15];
  const float* v3 = (const float*)d_in[16];
  float* out = (float*)d_out;

  k_prep<<<64, 256, 0, stream>>>(w1,g1,b1,m1,v1, w2,g2,b2,m2,v2, w3,g3,b3,m3,v3);
  k_soa<<<(BB*NN)/256, 256, 0, stream>>>(xyz);
  k_zero<<<64, 256, 0, stream>>>();
  k_fps<<<BB*FPS_NBLK, 512, 0, stream>>>(out);
  k_knn<<<512, 256, 0, stream>>>();
  k_mlp<<<BB*GG, 256, 0, stream>>>(xyz, feat, out + (size_t)BB*GG*3);
}